// Round 1
// 15729.530 us; speedup vs baseline: 1.6784x; 1.6784x over previous
//
#include <hip/hip_runtime.h>
#include <stdint.h>
#include <math.h>

// ---------------------------------------------------------------------------
// Encoder: 2-layer bidirectional GRU, B=64 T=256 H=1024 V=128, bf16 in/out
// (dtype auto-detected; fp32 fallback kept correct but not fast).
// Round N changes vs 26.4ms baseline:
//  * Whh-hi slice (96KB) + L0 Wih0 table (25KB) pinned in 124KB dynamic LDS
//    -> immune to the per-timestep L2 buffer_inv; weights fetched ONCE.
//  * Grid barrier: per-direction (64 blocks), 2-level arrival tree (8 subs),
//    single RELEASE gen store, s_sleep(8) polling, tid0-only
//    fence(release)/fence(acquire) instead of multiple __threadfence().
//  * hprev carried in registers (fp32 hf array removed).
//  * A-fragment loads (h hi/lo, 64x16B) fully issued per timestep into an
//    unrolled register array -> deep vmcnt pipeline over MALL latency.
//  * L0 token prefetch one step ahead; x-path loads issued at loop top.
// ---------------------------------------------------------------------------

#define B_  64
#define T_  256
#define H_  1024
#define G3_ 3072

#define WROW 1032                       // LDS weight row: 1024 + 8 pad (bank-spread)
#define SW_BYTES (48 * WROW * 2)        // 99072
#define SX_ROW 132                      // L0 table row: 128 + 4 pad
#define SMEM_BYTES (SW_BYTES + 48 * SX_ROW * 4)   // 124416

typedef __attribute__((ext_vector_type(8))) __bf16 bf16x8;
typedef __attribute__((ext_vector_type(4))) float  f32x4;

union FragU { uint4 u; bf16x8 b; };

__device__ __forceinline__ float bf2f(unsigned short v) {
  return __builtin_bit_cast(float, (uint32_t)v << 16);
}
__device__ __forceinline__ unsigned short f2bf(float f) {
  uint32_t u = __builtin_bit_cast(uint32_t, f);
  u += 0x7FFFu + ((u >> 16) & 1u);   // RNE (no NaN inputs here)
  return (unsigned short)(u >> 16);
}

// ---------------------------------------------------------------------------
// Per-direction grid barrier over 64 co-resident blocks.
// Layout (uint offsets from dir base, 128B line spacing):
//   [0]=master  [32*(1+i)],i<8 = sub-counters  [32*12] = gen
// Each wave's stores are drained by __syncthreads (vmcnt(0) before s_barrier);
// tid0's release fence (wbl2) pushes dirty L2 lines to MALL before arrival;
// acquire fence (buffer_inv) after release-detect makes subsequent normal
// loads fetch fresh data. Counters/gen are agent-scope atomics (MALL).
// ---------------------------------------------------------------------------
__device__ __forceinline__ void grid_bar(unsigned* bar, unsigned& lg) {
  __syncthreads();
  if (threadIdx.x == 0) {
    __builtin_amdgcn_fence(__ATOMIC_RELEASE, "agent");
    bool released = false;
    unsigned* sub = bar + 32u * (1u + (blockIdx.x & 7u));
    if (__hip_atomic_fetch_add(sub, 1u, __ATOMIC_RELAXED, __HIP_MEMORY_SCOPE_AGENT) == 7u) {
      if (__hip_atomic_fetch_add(bar, 1u, __ATOMIC_RELAXED, __HIP_MEMORY_SCOPE_AGENT) == 7u) {
        // full-barrier releaser: reset counters, then RELEASE-publish new gen
        __hip_atomic_store(bar, 0u, __ATOMIC_RELAXED, __HIP_MEMORY_SCOPE_AGENT);
#pragma unroll
        for (int i = 0; i < 8; ++i)
          __hip_atomic_store(bar + 32 * (1 + i), 0u, __ATOMIC_RELAXED, __HIP_MEMORY_SCOPE_AGENT);
        __hip_atomic_store(bar + 32 * 12, lg + 1u, __ATOMIC_RELEASE, __HIP_MEMORY_SCOPE_AGENT);
        released = true;
      }
    }
    if (!released) {
      unsigned spins = 0;
      while (__hip_atomic_load(bar + 32 * 12, __ATOMIC_RELAXED, __HIP_MEMORY_SCOPE_AGENT) == lg) {
        __builtin_amdgcn_s_sleep(8);
        if (++spins > (1u << 18)) break;   // safety valve (never hit when co-resident)
      }
    }
    __builtin_amdgcn_fence(__ATOMIC_ACQUIRE, "agent");
  }
  __syncthreads();
  ++lg;
}

// ---------------------------------------------------------------------------
// dtype detector: fp32 arrays' even uint16s are random mantissa halves;
// bf16 arrays' even uint16s are samples with |v|<=1/32 (exp field <= 122).
// ---------------------------------------------------------------------------
__global__ void detect_dtype(const unsigned short* __restrict__ p, int* __restrict__ flag) {
  const int i = threadIdx.x;                 // 0..63
  const unsigned short v = p[2 * i];
  const int e = (v >> 7) & 0xFF;
  const unsigned long long m = __ballot(e <= 124);
  if (i == 0) *flag = (m == ~0ull) ? 1 : 0;
}

__device__ __forceinline__ float load_canon(const void* src, int i, bool isbf) {
  return isbf ? bf2f(((const unsigned short*)src)[i]) : ((const float*)src)[i];
}

__global__ void prep_split(const void* __restrict__ src, int n,
                           unsigned short* __restrict__ hi, unsigned short* __restrict__ lo,
                           const int* __restrict__ flag) {
  const int i = blockIdx.x * blockDim.x + threadIdx.x;
  if (i >= n) return;
  const bool isbf = (*flag != 0);
  const float f = load_canon(src, i, isbf);
  const unsigned short h = f2bf(f);
  hi[i] = h;
  lo[i] = f2bf(f - bf2f(h));
}

__global__ void prep_f32(const void* __restrict__ src, int n,
                         float* __restrict__ dst, const int* __restrict__ flag) {
  const int i = blockIdx.x * blockDim.x + threadIdx.x;
  if (i >= n) return;
  const bool isbf = (*flag != 0);
  dst[i] = load_canon(src, i, isbf);
}

// ---------------------------------------------------------------------------
// Persistent GRU scan: one launch per layer, both directions.
// grid = (64 unit-tiles of 16, 2 dirs) = 128 blocks, block = 256 (4 waves).
// Wave w handles batch rows [16w,16w+16); 3 accumulators = r/z/n gates for
// units j0..j0+15.  MFMA maps (m89/m91): A[m=lane&15][k=(lane>>4)*8+e];
// B[n=lane&15][k]; D: row m=(lane>>4)*4+reg, col n=lane&15.
// ---------------------------------------------------------------------------
template<int LAYER>
__global__ __launch_bounds__(256, 1) void gru_scan(
    const int*            __restrict__ x,       // (64,256) tokens
    const float*          __restrict__ Wih0f,   // L0: (2,3072,128) fp32
    const float*          __restrict__ bihf,    // L0: (2,3072) fp32
    const _Float16*       __restrict__ xp1,     // L1: (2,16384,3072) fp16
    const unsigned short* __restrict__ WhhH,    // (2,3072,1024) bf16 hi
    const unsigned short* __restrict__ WhhL,    // bf16 lo
    const float*          __restrict__ bhhf,    // (2,3072) fp32
    unsigned short*       __restrict__ hhi,     // [2 slots][2,64,1024] bf16 hi
    unsigned short*       __restrict__ hlo,
    unsigned short*       __restrict__ ys0_hi,  // L0 out: (64,256,2048)
    unsigned short*       __restrict__ ys0_lo,
    void*                 __restrict__ d_out,   // L1 out + hiddens
    const int*            __restrict__ flag,
    unsigned*             __restrict__ bar_mem)
{
  extern __shared__ unsigned char smem[];
  unsigned short* sW = (unsigned short*)smem;            // [48][WROW] bf16
  float*          sX = (float*)(smem + SW_BYTES);        // L0: [48][SX_ROW] f32

  const int j0   = blockIdx.x << 4;       // unit tile base (16 units)
  const int d    = blockIdx.y;
  const int tid  = threadIdx.x;
  const int w    = tid >> 6;
  const int lane = tid & 63;
  const int quad = lane >> 4, l15 = lane & 15;
  const bool out_bf = (*flag != 0);
  const bool wlo    = (*flag == 0);       // weight-lo terms only for fp32 inputs

  const int j = j0 + l15;                 // this lane's unit
  const size_t HF_HALF = (size_t)2 * B_ * H_;

  // ---- stage Whh-hi slice (48 rows x 1024) into LDS, once ----
  {
    const unsigned short* base = WhhH + (size_t)d * G3_ * H_;
    for (int idx = tid; idx < 48 * 128; idx += 256) {
      const int row = idx >> 7, c = (idx & 127) << 3;
      const int g = row >> 4, u = row & 15;
      const uint4 v = *(const uint4*)(base + (size_t)(g * H_ + j0 + u) * H_ + c);
      *(uint4*)&sW[row * WROW + c] = v;
    }
  }
  if (LAYER == 0) {
    // stage the 48 Wih0 gather rows (128 f32 each) into LDS, once
    const float* W0 = Wih0f + (size_t)d * G3_ * 128;
    for (int idx = tid; idx < 48 * 32; idx += 256) {
      const int row = idx >> 5, c = (idx & 31) << 2;
      const int g = row >> 4, u = row & 15;
      const float4 v = *(const float4*)(W0 + (size_t)(g * H_ + j0 + u) * 128 + c);
      *(float4*)&sX[row * SX_ROW + c] = v;
    }
  }
  __syncthreads();

  // ---- loop-invariant pointers ----
  const int am = (w << 4) + l15;          // A-frag batch row
  const unsigned short *aphS[2], *aplS[2];
  unsigned short *hhiS[2], *hloS[2];
#pragma unroll
  for (int s = 0; s < 2; ++s) {
    aphS[s] = hhi + s * HF_HALF + ((size_t)d * B_ + am) * H_ + (quad << 3);
    aplS[s] = hlo + s * HF_HALF + ((size_t)d * B_ + am) * H_ + (quad << 3);
    hhiS[s] = hhi + s * HF_HALF + (size_t)d * B_ * H_;
    hloS[s] = hlo + s * HF_HALF + (size_t)d * B_ * H_;
  }

  const unsigned short* sBp[3];           // LDS weight fragments
  const unsigned short* bplG[3];          // global lo-weight rows (fp32 path)
#pragma unroll
  for (int g = 0; g < 3; ++g) {
    sBp[g]  = sW + (g * 16 + l15) * WROW + (quad << 3);
    bplG[g] = WhhL + (size_t)d * G3_ * H_ + (size_t)(g * H_ + j) * H_ + (quad << 3);
  }

  const size_t dj = (size_t)d * G3_ + j;
  const float bhr = bhhf[dj];
  const float bhz = bhhf[dj + H_];
  const float bhn = bhhf[dj + 2 * H_];
  float bir = 0.f, biz = 0.f, bin_ = 0.f;
  const float *sXr = nullptr, *sXz = nullptr, *sXn = nullptr;
  if (LAYER == 0) {
    bir  = bihf[dj];
    biz  = bihf[dj + H_];
    bin_ = bihf[dj + 2 * H_];
    sXr = sX + (size_t)l15 * SX_ROW;
    sXz = sX + (size_t)(16 + l15) * SX_ROW;
    sXn = sX + (size_t)(32 + l15) * SX_ROW;
  }
  const _Float16* xpd = (LAYER == 1) ? (xp1 + (size_t)d * (B_ * T_) * G3_) : nullptr;

  float*          out_f  = (float*)d_out;
  unsigned short* out_b  = (unsigned short*)d_out;
  const size_t    HIDOFF = (size_t)B_ * T_ * 2048;

  unsigned* bar = bar_mem + (size_t)d * 512;   // per-dir barrier (2048B apart)
  unsigned lg = 0;

  float hprev[4] = {0.f, 0.f, 0.f, 0.f};       // register h-carry (exact fp32)
  int ptok[4];
  if (LAYER == 0) {
    const int te0 = d ? (T_ - 1) : 0;
#pragma unroll
    for (int r = 0; r < 4; ++r)
      ptok[r] = x[((w << 4) + (quad << 2) + r) * T_ + te0];
  }

  for (int t = 0; t < T_; ++t) {
    const int t_eff = d ? (T_ - 1 - t) : t;
    const int pi = t & 1, po = pi ^ 1;

    // ---- x-path (issued early, overlaps k-loop) ----
    float xr[4], xz[4], xn[4];
    if (LAYER == 0) {
#pragma unroll
      for (int r = 0; r < 4; ++r) {
        const int tok = ptok[r];
        xr[r] = sXr[tok] + bir;
        xz[r] = sXz[tok] + biz;
        xn[r] = sXn[tok] + bin_;
      }
      if (t + 1 < T_) {                        // prefetch tokens for t+1
        const int te = d ? (T_ - 2 - t) : (t + 1);
#pragma unroll
        for (int r = 0; r < 4; ++r)
          ptok[r] = x[((w << 4) + (quad << 2) + r) * T_ + te];
      }
    } else {
#pragma unroll
      for (int r = 0; r < 4; ++r) {
        const int b = (w << 4) + (quad << 2) + r;
        const _Float16* xp = xpd + ((size_t)b * T_ + t_eff) * G3_;
        xr[r] = (float)xp[j];
        xz[r] = (float)xp[j + H_];
        xn[r] = (float)xp[j + 2 * H_];
      }
    }

    // ---- full-issue A loads: 64 x uint4, deep vmcnt pipeline ----
    const unsigned short* aph = aphS[pi];
    const unsigned short* apl = aplS[pi];
    FragU ah[32], al[32];
#pragma unroll
    for (int kt = 0; kt < 32; ++kt) {
      ah[kt].u = *(const uint4*)(aph + kt * 32);
      al[kt].u = *(const uint4*)(apl + kt * 32);
    }

    f32x4 acc[3] = {};
    if (wlo) {
#pragma unroll
      for (int kt = 0; kt < 32; ++kt)
#pragma unroll
        for (int g = 0; g < 3; ++g) {
          FragU fb; fb.u = *(const uint4*)(sBp[g]  + kt * 32);
          FragU fl; fl.u = *(const uint4*)(bplG[g] + kt * 32);
          acc[g] = __builtin_amdgcn_mfma_f32_16x16x32_bf16(ah[kt].b, fb.b, acc[g], 0, 0, 0);
          acc[g] = __builtin_amdgcn_mfma_f32_16x16x32_bf16(al[kt].b, fb.b, acc[g], 0, 0, 0);
          acc[g] = __builtin_amdgcn_mfma_f32_16x16x32_bf16(ah[kt].b, fl.b, acc[g], 0, 0, 0);
        }
    } else {
#pragma unroll
      for (int kt = 0; kt < 32; ++kt)
#pragma unroll
        for (int g = 0; g < 3; ++g) {
          FragU fb; fb.u = *(const uint4*)(sBp[g] + kt * 32);
          acc[g] = __builtin_amdgcn_mfma_f32_16x16x32_bf16(ah[kt].b, fb.b, acc[g], 0, 0, 0);
          acc[g] = __builtin_amdgcn_mfma_f32_16x16x32_bf16(al[kt].b, fb.b, acc[g], 0, 0, 0);
        }
    }

    // ---- gate math: 4 (b, j) pairs per lane ----
#pragma unroll
    for (int r = 0; r < 4; ++r) {
      const int b = (w << 4) + (quad << 2) + r;
      const float gr = acc[0][r] + bhr;
      const float gz = acc[1][r] + bhz;
      const float gn = acc[2][r] + bhn;

      const float rg = 1.f / (1.f + expf(-(xr[r] + gr)));
      const float zg = 1.f / (1.f + expf(-(xz[r] + gz)));
      const float ng = tanhf(xn[r] + rg * gn);
      const float hnew = (1.f - zg) * ng + zg * hprev[r];
      hprev[r] = hnew;

      const size_t ho = (size_t)b * H_ + j;
      const unsigned short hi = f2bf(hnew);
      const unsigned short lo = f2bf(hnew - bf2f(hi));
      hhiS[po][ho] = hi;
      hloS[po][ho] = lo;

      const size_t yoff = ((size_t)b * T_ + t_eff) * 2048 + d * H_ + j;
      if (LAYER == 0) {
        ys0_hi[yoff] = hi;
        ys0_lo[yoff] = lo;
      } else {
        if (out_bf) out_b[yoff] = hi; else out_f[yoff] = hnew;
      }
      if (t == T_ - 1) {
        const size_t hh = HIDOFF + ((size_t)(LAYER * 2 + d) * B_ + b) * H_ + j;
        if (out_bf) out_b[hh] = hi; else out_f[hh] = hnew;
      }
    }

    if (t + 1 < T_) grid_bar(bar, lg);   // last step needs no exchange
  }
}

// ---------------------------------------------------------------------------
// xp1 = ys0cat @ Wih1[d]^T + bih1[d], fp16 out.  M=16384 N=3072 K=2048, x2 dirs.
// 128x128 tile, BK=32; A hi/lo always, B lo only when inputs were fp32.
// ---------------------------------------------------------------------------
__global__ __launch_bounds__(256) void xp1_gemm(
    const unsigned short* __restrict__ Ahi,    // (16384,2048) ys0 hi
    const unsigned short* __restrict__ Alo,    // ys0 lo
    const unsigned short* __restrict__ Bhi,    // (2,3072,2048) Wih1 hi
    const unsigned short* __restrict__ Blo,    // Wih1 lo
    const float*          __restrict__ biasf,  // (2,3072) fp32
    _Float16*             __restrict__ xp1,    // (2,16384,3072)
    const int*            __restrict__ flag)
{
  const int nt  = blockIdx.x;
  const int mt  = blockIdx.y;
  const int d   = blockIdx.z;
  const int tid = threadIdx.x;
  const int w = tid >> 6, lane = tid & 63;
  const int quad = lane >> 4, l15 = lane & 15;
  const int wm = w >> 1, wn = w & 1;
  const bool wlo = (*flag == 0);

  __shared__ unsigned short sAh[128][40];  // +8 pad: 80B row stride
  __shared__ unsigned short sAl[128][40];
  __shared__ unsigned short sBh[128][40];
  __shared__ unsigned short sBl[128][40];

  const int srow = tid >> 1;
  const int scol = (tid & 1) << 4;
  const unsigned short* gAh = Ahi + (size_t)(mt * 128 + srow) * 2048 + scol;
  const unsigned short* gAl = Alo + (size_t)(mt * 128 + srow) * 2048 + scol;
  const unsigned short* gBh = Bhi + (size_t)d * G3_ * 2048
                                  + (size_t)(nt * 128 + srow) * 2048 + scol;
  const unsigned short* gBl = Blo + (size_t)d * G3_ * 2048
                                  + (size_t)(nt * 128 + srow) * 2048 + scol;

  f32x4 acc[4][4] = {};

  for (int k0 = 0; k0 < 2048; k0 += 32) {
    const uint4 a0 = *(const uint4*)(gAh + k0);
    const uint4 a1 = *(const uint4*)(gAh + k0 + 8);
    const uint4 l0 = *(const uint4*)(gAl + k0);
    const uint4 l1 = *(const uint4*)(gAl + k0 + 8);
    const uint4 b0 = *(const uint4*)(gBh + k0);
    const uint4 b1 = *(const uint4*)(gBh + k0 + 8);
    uint4 c0, c1;
    if (wlo) { c0 = *(const uint4*)(gBl + k0); c1 = *(const uint4*)(gBl + k0 + 8); }
    __syncthreads();                       // previous iter's LDS reads done
    *(uint4*)&sAh[srow][scol]     = a0;
    *(uint4*)&sAh[srow][scol + 8] = a1;
    *(uint4*)&sAl[srow][scol]     = l0;
    *(uint4*)&sAl[srow][scol + 8] = l1;
    *(uint4*)&sBh[srow][scol]     = b0;
    *(uint4*)&sBh[srow][scol + 8] = b1;
    if (wlo) {
      *(uint4*)&sBl[srow][scol]     = c0;
      *(uint4*)&sBl[srow][scol + 8] = c1;
    }
    __syncthreads();

    bf16x8 fah[4], fal[4], fbh[4];
#pragma unroll
    for (int i = 0; i < 4; ++i) {
      FragU fa; fa.u = *(const uint4*)&sAh[(wm << 6) + (i << 4) + l15][quad << 3]; fah[i] = fa.b;
      FragU fl; fl.u = *(const uint4*)&sAl[(wm << 6) + (i << 4) + l15][quad << 3]; fal[i] = fl.b;
      FragU fb; fb.u = *(const uint4*)&sBh[(wn << 6) + (i << 4) + l15][quad << 3]; fbh[i] = fb.b;
    }
#pragma unroll
    for (int i = 0; i < 4; ++i)
#pragma unroll
      for (int jj = 0; jj < 4; ++jj) {
        acc[i][jj] = __builtin_amdgcn_mfma_f32_16x16x32_bf16(fah[i], fbh[jj], acc[i][jj], 0, 0, 0);
        acc[i][jj] = __builtin_amdgcn_mfma_f32_16x16x32_bf16(fal[i], fbh[jj], acc[i][jj], 0, 0, 0);
      }
    if (wlo) {
#pragma unroll
      for (int jj = 0; jj < 4; ++jj) {
        FragU fc; fc.u = *(const uint4*)&sBl[(wn << 6) + (jj << 4) + l15][quad << 3];
#pragma unroll
        for (int i = 0; i < 4; ++i)
          acc[i][jj] = __builtin_amdgcn_mfma_f32_16x16x32_bf16(fah[i], fc.b, acc[i][jj], 0, 0, 0);
      }
    }
  }

#pragma unroll
  for (int jj = 0; jj < 4; ++jj) {
    const int col = nt * 128 + (wn << 6) + (jj << 4) + l15;
    const float bias = biasf[(size_t)d * G3_ + col];
#pragma unroll
    for (int i = 0; i < 4; ++i) {
      const int m = mt * 128 + (wm << 6) + (i << 4) + (quad << 2);
      _Float16* op = xp1 + ((size_t)d * (B_ * T_) + m) * G3_ + col;
#pragma unroll
      for (int r = 0; r < 4; ++r) op[(size_t)r * G3_] = (_Float16)(acc[i][jj][r] + bias);
    }
  }
}

// ---------------------------------------------------------------------------
extern "C" void kernel_launch(void* const* d_in, const int* in_sizes, int n_in,
                              void* d_out, int out_size, void* d_ws, size_t ws_size,
                              hipStream_t stream)
{
  const int*  x    = (const int*)d_in[0];
  const void* Wih0 = d_in[1];   // (2,3072,128)
  const void* Whh0 = d_in[2];   // (2,3072,1024)
  const void* bih0 = d_in[3];   // (2,3072)
  const void* bhh0 = d_in[4];
  const void* Wih1 = d_in[5];   // (2,3072,2048)
  const void* Whh1 = d_in[6];   // (2,3072,1024)
  const void* bih1 = d_in[7];
  const void* bhh1 = d_in[8];

  // ---- workspace carve ----
  const size_t FLAG_B = 256;
  const size_t XP1_B  = (size_t)2 * B_ * T_ * G3_ * 2;    // fp16: 201,326,592
  const size_t YS_B   = (size_t)B_ * T_ * 2048 * 2;       // 67,108,864 (each)
  const size_t WHH_B  = (size_t)2 * G3_ * H_ * 2;         // 12,582,912 (each)
  const size_t WIH1_B = (size_t)2 * G3_ * 2048 * 2;       // 25,165,824 (each)
  const size_t WIH0_B = (size_t)2 * G3_ * 128 * 4;        // 3,145,728
  const size_t BIAS_B = (size_t)2 * G3_ * 4;              // 24,576 (each of 4)
  const size_t HB_B   = (size_t)2 * 2 * B_ * H_ * 2;      // 524,288 (each of hi/lo)
  const size_t BAR_B  = 4096;
  const size_t NEED = FLAG_B + XP1_B + 2 * YS_B + 4 * WHH_B + 2 * WIH1_B
                    + WIH0_B + 4 * BIAS_B + 2 * HB_B + BAR_B;
  if (ws_size < NEED) return;   // diagnostic: output stays zero

  char* p = (char*)d_ws;
  int*            flag    = (int*)p;            p += FLAG_B;
  _Float16*       xp1     = (_Float16*)p;       p += XP1_B;
  unsigned short* ys0_hi  = (unsigned short*)p; p += YS_B;
  unsigned short* ys0_lo  = (unsigned short*)p; p += YS_B;
  unsigned short* Whh0H   = (unsigned short*)p; p += WHH_B;
  unsigned short* Whh0L   = (unsigned short*)p; p += WHH_B;
  unsigned short* Whh1H   = (unsigned short*)p; p += WHH_B;
  unsigned short* Whh1L   = (unsigned short*)p; p += WHH_B;
  unsigned short* Wih1H   = (unsigned short*)p; p += WIH1_B;
  unsigned short* Wih1L   = (unsigned short*)p; p += WIH1_B;
  float*          Wih0f   = (float*)p;          p += WIH0_B;
  float*          bih0f   = (float*)p;          p += BIAS_B;
  float*          bhh0f   = (float*)p;          p += BIAS_B;
  float*          bih1f   = (float*)p;          p += BIAS_B;
  float*          bhh1f   = (float*)p;          p += BIAS_B;
  char*           hbase   = p;
  unsigned short* hhi     = (unsigned short*)hbase;
  unsigned short* hlo     = (unsigned short*)(hbase + HB_B);
  unsigned*       bar     = (unsigned*)(hbase + 2 * HB_B);

  // ---- allow 124KB dynamic LDS for the scan kernels (idempotent) ----
  hipFuncSetAttribute((const void*)&gru_scan<0>,
                      hipFuncAttributeMaxDynamicSharedMemorySize, SMEM_BYTES);
  hipFuncSetAttribute((const void*)&gru_scan<1>,
                      hipFuncAttributeMaxDynamicSharedMemorySize, SMEM_BYTES);

  // ---- dtype detect + canonicalize ----
  detect_dtype<<<1, 64, 0, stream>>>((const unsigned short*)bih0, flag);

  const int NWHH  = 2 * G3_ * H_;
  const int NWIH1 = 2 * G3_ * 2048;
  const int NWIH0 = 2 * G3_ * 128;
  const int NBIAS = 2 * G3_;
  prep_split<<<(NWHH  + 255) / 256, 256, 0, stream>>>(Whh0, NWHH,  Whh0H, Whh0L, flag);
  prep_split<<<(NWHH  + 255) / 256, 256, 0, stream>>>(Whh1, NWHH,  Whh1H, Whh1L, flag);
  prep_split<<<(NWIH1 + 255) / 256, 256, 0, stream>>>(Wih1, NWIH1, Wih1H, Wih1L, flag);
  prep_f32<<<(NWIH0 + 255) / 256, 256, 0, stream>>>(Wih0, NWIH0, Wih0f, flag);
  prep_f32<<<(NBIAS + 255) / 256, 256, 0, stream>>>(bih0, NBIAS, bih0f, flag);
  prep_f32<<<(NBIAS + 255) / 256, 256, 0, stream>>>(bhh0, NBIAS, bhh0f, flag);
  prep_f32<<<(NBIAS + 255) / 256, 256, 0, stream>>>(bih1, NBIAS, bih1f, flag);
  prep_f32<<<(NBIAS + 255) / 256, 256, 0, stream>>>(bhh1, NBIAS, bhh1f, flag);

  // ---- layer 0 scan (persistent, per-dir grid barrier) ----
  hipMemsetAsync(hbase, 0, 2 * HB_B + BAR_B, stream);
  gru_scan<0><<<dim3(64, 2), 256, SMEM_BYTES, stream>>>(
      x, Wih0f, bih0f, nullptr, Whh0H, Whh0L, bhh0f,
      hhi, hlo, ys0_hi, ys0_lo, d_out, flag, bar);

  // ---- layer-1 input projection ----
  xp1_gemm<<<dim3(24, 128, 2), 256, 0, stream>>>(ys0_hi, ys0_lo, Wih1H, Wih1L, bih1f, xp1, flag);

  // ---- layer 1 scan ----
  hipMemsetAsync(hbase, 0, 2 * HB_B + BAR_B, stream);
  gru_scan<1><<<dim3(64, 2), 256, SMEM_BYTES, stream>>>(
      x, nullptr, nullptr, xp1, Whh1H, Whh1L, bhh1f,
      hhi, hlo, nullptr, nullptr, d_out, flag, bar);
}

// Round 2
// 10998.952 us; speedup vs baseline: 2.4003x; 1.4301x over previous
//
#include <hip/hip_runtime.h>
#include <stdint.h>
#include <math.h>

// ---------------------------------------------------------------------------
// Encoder: 2-layer bidirectional GRU, B=64 T=256 H=1024 V=128, bf16 in/out
// (dtype auto-detected; fp32 fallback kept correct but not fast).
// Round-2 changes vs 15.7ms:
//  * Fence-FREE per-step sync: h hi/lo exchanged via sc0/sc1 (MALL-coherent,
//    L2-bypass) inline-asm loads/stores -> no buffer_wbl2/buffer_inv per step.
//    Barrier = single per-direction monotonic relaxed atomic counter + poll.
//  * Fragment-major LDS weight layout (conflict-free ds_read_b128).
//  * x-path loads for step t+1 issued BEFORE the barrier (latency hidden).
//  * Counted vmcnt(32)/vmcnt(0) waits over the 64 asm h-loads (in-order
//    vmem completion), sched_barrier(0) after each wait (rule #18).
//  * fp32-input fallback path keeps fenced barrier + cached h (correct, slow).
// ---------------------------------------------------------------------------

#define B_  64
#define T_  256
#define H_  1024
#define G3_ 3072

#define SW_BYTES (3 * 32 * 64 * 16)               // 98304: [g][kt][lane] 16B frags
#define SX_ROW 132                                // L0 table row: 128 + 4 pad
#define SMEM_BYTES (SW_BYTES + 48 * SX_ROW * 4)   // 123648

typedef __attribute__((ext_vector_type(8))) __bf16 bf16x8;
typedef __attribute__((ext_vector_type(4))) float  f32x4;

union FragU { uint4 u; bf16x8 b; };

__device__ __forceinline__ float bf2f(unsigned short v) {
  return __builtin_bit_cast(float, (uint32_t)v << 16);
}
__device__ __forceinline__ unsigned short f2bf(float f) {
  uint32_t u = __builtin_bit_cast(uint32_t, f);
  u += 0x7FFFu + ((u >> 16) & 1u);   // RNE (no NaN inputs here)
  return (unsigned short)(u >> 16);
}

// ---------------------------------------------------------------------------
// Barriers over the 64 co-resident blocks of one direction.
// bar_fast: NO cache maintenance. All cross-block data moves via sc0/sc1
// (MALL) accesses; vmcnt(0) before s_barrier makes stores MALL-visible
// before the relaxed arrival add. Counter is monotonic (64 per step).
// bar_fenced: fp32-input fallback (normal cached h): wbl2/inv per step.
// ---------------------------------------------------------------------------
__device__ __forceinline__ void bar_fast(unsigned* cnt, unsigned& target) {
  asm volatile("s_waitcnt vmcnt(0)" ::: "memory");
  __syncthreads();
  if (threadIdx.x == 0) {
    __hip_atomic_fetch_add(cnt, 1u, __ATOMIC_RELAXED, __HIP_MEMORY_SCOPE_AGENT);
    unsigned spins = 0;
    while (__hip_atomic_load(cnt, __ATOMIC_RELAXED, __HIP_MEMORY_SCOPE_AGENT) < target) {
      __builtin_amdgcn_s_sleep(2);
      if (++spins > (1u << 22)) break;   // safety valve (never hit when co-resident)
    }
  }
  __syncthreads();
  target += 64;
}

__device__ __forceinline__ void bar_fenced(unsigned* cnt, unsigned& target) {
  __syncthreads();
  if (threadIdx.x == 0) {
    __builtin_amdgcn_fence(__ATOMIC_RELEASE, "agent");
    __hip_atomic_fetch_add(cnt, 1u, __ATOMIC_RELAXED, __HIP_MEMORY_SCOPE_AGENT);
    unsigned spins = 0;
    while (__hip_atomic_load(cnt, __ATOMIC_RELAXED, __HIP_MEMORY_SCOPE_AGENT) < target) {
      __builtin_amdgcn_s_sleep(8);
      if (++spins > (1u << 20)) break;
    }
    __builtin_amdgcn_fence(__ATOMIC_ACQUIRE, "agent");
  }
  __syncthreads();
  target += 64;
}

// ---------------------------------------------------------------------------
// dtype detector: fp32 arrays' even uint16s are random mantissa halves;
// bf16 arrays' even uint16s are samples with small exponents.
// ---------------------------------------------------------------------------
__global__ void detect_dtype(const unsigned short* __restrict__ p, int* __restrict__ flag) {
  const int i = threadIdx.x;                 // 0..63
  const unsigned short v = p[2 * i];
  const int e = (v >> 7) & 0xFF;
  const unsigned long long m = __ballot(e <= 124);
  if (i == 0) *flag = (m == ~0ull) ? 1 : 0;
}

__device__ __forceinline__ float load_canon(const void* src, int i, bool isbf) {
  return isbf ? bf2f(((const unsigned short*)src)[i]) : ((const float*)src)[i];
}

__global__ void prep_split(const void* __restrict__ src, int n,
                           unsigned short* __restrict__ hi, unsigned short* __restrict__ lo,
                           const int* __restrict__ flag) {
  const int i = blockIdx.x * blockDim.x + threadIdx.x;
  if (i >= n) return;
  const bool isbf = (*flag != 0);
  const float f = load_canon(src, i, isbf);
  const unsigned short h = f2bf(f);
  hi[i] = h;
  lo[i] = f2bf(f - bf2f(h));
}

__global__ void prep_f32(const void* __restrict__ src, int n,
                         float* __restrict__ dst, const int* __restrict__ flag) {
  const int i = blockIdx.x * blockDim.x + threadIdx.x;
  if (i >= n) return;
  const bool isbf = (*flag != 0);
  dst[i] = load_canon(src, i, isbf);
}

// ---------------------------------------------------------------------------
// sc0/sc1 inline-asm access macros (MALL-coherent, bypass L1/L2).
// ---------------------------------------------------------------------------
#define LD2(K, OFF)                                                         \
  asm volatile("global_load_dwordx4 %0, %2, off offset:" OFF " sc0 sc1\n\t" \
               "global_load_dwordx4 %1, %3, off offset:" OFF " sc0 sc1"     \
               : "=&v"(ah[K].u), "=&v"(al[K].u)                             \
               : "v"(aph), "v"(apl));

#define STH(P, V)                                                 \
  asm volatile("global_store_short %0, %1, off sc0 sc1"           \
               :: "v"(P), "v"(V) : "memory");

// ---------------------------------------------------------------------------
// Persistent GRU scan: one launch per layer, both directions.
// grid = (64 unit-tiles of 16, 2 dirs) = 128 blocks, block = 256 (4 waves).
// Wave w handles batch rows [16w,16w+16); 3 accumulators = r/z/n gates for
// units j0..j0+15.  MFMA maps (m89/m91): A[m=lane&15][k=(lane>>4)*8+e];
// B[n=lane&15][k]; D: row m=(lane>>4)*4+reg, col n=lane&15.
// ---------------------------------------------------------------------------
template<int LAYER>
__global__ __launch_bounds__(256, 1) void gru_scan(
    const int*            __restrict__ x,       // (64,256) tokens
    const float*          __restrict__ Wih0f,   // L0: (2,3072,128) fp32
    const float*          __restrict__ bihf,    // L0: (2,3072) fp32
    const _Float16*       __restrict__ xp1,     // L1: (2,16384,3072) fp16
    const unsigned short* __restrict__ WhhH,    // (2,3072,1024) bf16 hi
    const unsigned short* __restrict__ WhhL,    // bf16 lo
    const float*          __restrict__ bhhf,    // (2,3072) fp32
    unsigned short*       __restrict__ hhi,     // [2 slots][2,64,1024] bf16 hi
    unsigned short*       __restrict__ hlo,
    unsigned short*       __restrict__ ys0_hi,  // L0 out: (64,256,2048)
    unsigned short*       __restrict__ ys0_lo,
    void*                 __restrict__ d_out,   // L1 out + hiddens
    const int*            __restrict__ flag,
    unsigned*             __restrict__ bar_mem)
{
  extern __shared__ unsigned char smem[];
  unsigned short* sW = (unsigned short*)smem;            // fragment-major weights
  float*          sX = (float*)(smem + SW_BYTES);        // L0: [48][SX_ROW] f32

  const int j0   = blockIdx.x << 4;       // unit tile base (16 units)
  const int d    = blockIdx.y;
  const int tid  = threadIdx.x;
  const int w    = tid >> 6;
  const int lane = tid & 63;
  const int quad = lane >> 4, l15 = lane & 15;
  const bool out_bf = (*flag != 0);
  const bool wlo    = (*flag == 0);       // weight-lo terms only for fp32 inputs

  const int j = j0 + l15;                 // this lane's unit
  const size_t HF_HALF = (size_t)2 * B_ * H_;

  // ---- stage Whh-hi slice fragment-major: sW[((g*32+kt)*64 + q*16+u)*8] ----
  {
    const unsigned short* base = WhhH + (size_t)d * G3_ * H_;
    for (int idx = tid; idx < 48 * 128; idx += 256) {
      const int row = idx >> 7;            // 0..47 = g*16+u
      const int c16 = idx & 127;           // 8-short chunk: k = c16*8
      const int g = row >> 4, u = row & 15;
      const int kt = c16 >> 2, q = c16 & 3;
      const uint4 v = *(const uint4*)(base + (size_t)(g * H_ + j0 + u) * H_ + (c16 << 3));
      *(uint4*)&sW[(((g << 5) + kt) << 9) + (((q << 4) + u) << 3)] = v;
    }
  }
  if (LAYER == 0) {
    const float* W0 = Wih0f + (size_t)d * G3_ * 128;
    for (int idx = tid; idx < 48 * 32; idx += 256) {
      const int row = idx >> 5, c = (idx & 31) << 2;
      const int g = row >> 4, u = row & 15;
      const float4 v = *(const float4*)(W0 + (size_t)(g * H_ + j0 + u) * 128 + c);
      *(float4*)&sX[row * SX_ROW + c] = v;
    }
  }
  __syncthreads();

  // ---- loop-invariant pointers ----
  const int am = (w << 4) + l15;          // A-frag batch row
  const unsigned short *aphS[2], *aplS[2];
  unsigned short *hhiS[2], *hloS[2];
#pragma unroll
  for (int s = 0; s < 2; ++s) {
    aphS[s] = hhi + s * HF_HALF + ((size_t)d * B_ + am) * H_ + (quad << 3);
    aplS[s] = hlo + s * HF_HALF + ((size_t)d * B_ + am) * H_ + (quad << 3);
    hhiS[s] = hhi + s * HF_HALF + (size_t)d * B_ * H_;
    hloS[s] = hlo + s * HF_HALF + (size_t)d * B_ * H_;
  }

  const unsigned short* bplG[3];          // global lo-weight rows (fp32 path)
#pragma unroll
  for (int g = 0; g < 3; ++g)
    bplG[g] = WhhL + (size_t)d * G3_ * H_ + (size_t)(g * H_ + j) * H_ + (quad << 3);

  const size_t dj = (size_t)d * G3_ + j;
  const float bhr = bhhf[dj];
  const float bhz = bhhf[dj + H_];
  const float bhn = bhhf[dj + 2 * H_];
  float bir = 0.f, biz = 0.f, bin_ = 0.f;
  const float *sXr = nullptr, *sXz = nullptr, *sXn = nullptr;
  if (LAYER == 0) {
    bir  = bihf[dj];
    biz  = bihf[dj + H_];
    bin_ = bihf[dj + 2 * H_];
    sXr = sX + (size_t)l15 * SX_ROW;
    sXz = sX + (size_t)(16 + l15) * SX_ROW;
    sXn = sX + (size_t)(32 + l15) * SX_ROW;
  }
  const _Float16* xpd = (LAYER == 1) ? (xp1 + (size_t)d * (B_ * T_) * G3_) : nullptr;

  float*          out_f  = (float*)d_out;
  unsigned short* out_b  = (unsigned short*)d_out;
  const size_t    HIDOFF = (size_t)B_ * T_ * 2048;

  unsigned* cnt = bar_mem + (size_t)d * 256;   // per-dir counter, 1KB apart
  unsigned target = 64;
  const int bb = (w << 4) + (quad << 2);       // this lane's 4 batch rows
  float hprev[4] = {0.f, 0.f, 0.f, 0.f};       // register h-carry (exact fp32)

  if (!wlo) {
    // =======================  FAST PATH (bf16 inputs)  =====================
    float xr[4], xz[4], xn[4];
    _Float16 xph[12];
    {   // prologue x for t=0
      const int te = d ? (T_ - 1) : 0;
      if (LAYER == 0) {
#pragma unroll
        for (int r = 0; r < 4; ++r) {
          const int tok = x[(bb + r) * T_ + te];
          xr[r] = sXr[tok] + bir; xz[r] = sXz[tok] + biz; xn[r] = sXn[tok] + bin_;
        }
      } else {
#pragma unroll
        for (int r = 0; r < 4; ++r) {
          const _Float16* xpb = xpd + ((size_t)(bb + r) * T_ + te) * G3_;
          xph[r * 3 + 0] = xpb[j]; xph[r * 3 + 1] = xpb[j + H_]; xph[r * 3 + 2] = xpb[j + 2 * H_];
        }
      }
    }

    for (int t = 0; t < T_; ++t) {
      const int t_eff = d ? (T_ - 1 - t) : t;
      const int pi = t & 1, po = pi ^ 1;
      const unsigned short* aph = aphS[pi];
      const unsigned short* apl = aplS[pi];

      // ---- issue all 64 sc1 h-loads (deep in-order vmem pipeline) ----
      FragU ah[32], al[32];
      LD2(0, "0")    LD2(1, "64")   LD2(2, "128")  LD2(3, "192")
      LD2(4, "256")  LD2(5, "320")  LD2(6, "384")  LD2(7, "448")
      LD2(8, "512")  LD2(9, "576")  LD2(10, "640") LD2(11, "704")
      LD2(12, "768") LD2(13, "832") LD2(14, "896") LD2(15, "960")
      LD2(16, "1024") LD2(17, "1088") LD2(18, "1152") LD2(19, "1216")
      LD2(20, "1280") LD2(21, "1344") LD2(22, "1408") LD2(23, "1472")
      LD2(24, "1536") LD2(25, "1600") LD2(26, "1664") LD2(27, "1728")
      LD2(28, "1792") LD2(29, "1856") LD2(30, "1920") LD2(31, "1984")

      f32x4 acc[3] = {};
      asm volatile("s_waitcnt vmcnt(32)" ::: "memory");   // first 32 loads done
      __builtin_amdgcn_sched_barrier(0);
#pragma unroll
      for (int kt = 0; kt < 16; ++kt) {
        FragU f0, f1, f2;
        f0.u = *(const uint4*)(sW + ((kt      ) << 9) + (lane << 3));
        f1.u = *(const uint4*)(sW + ((kt +  32) << 9) + (lane << 3));
        f2.u = *(const uint4*)(sW + ((kt +  64) << 9) + (lane << 3));
        acc[0] = __builtin_amdgcn_mfma_f32_16x16x32_bf16(ah[kt].b, f0.b, acc[0], 0, 0, 0);
        acc[0] = __builtin_amdgcn_mfma_f32_16x16x32_bf16(al[kt].b, f0.b, acc[0], 0, 0, 0);
        acc[1] = __builtin_amdgcn_mfma_f32_16x16x32_bf16(ah[kt].b, f1.b, acc[1], 0, 0, 0);
        acc[1] = __builtin_amdgcn_mfma_f32_16x16x32_bf16(al[kt].b, f1.b, acc[1], 0, 0, 0);
        acc[2] = __builtin_amdgcn_mfma_f32_16x16x32_bf16(ah[kt].b, f2.b, acc[2], 0, 0, 0);
        acc[2] = __builtin_amdgcn_mfma_f32_16x16x32_bf16(al[kt].b, f2.b, acc[2], 0, 0, 0);
      }
      asm volatile("s_waitcnt vmcnt(0)" ::: "memory");
      __builtin_amdgcn_sched_barrier(0);
#pragma unroll
      for (int kt = 16; kt < 32; ++kt) {
        FragU f0, f1, f2;
        f0.u = *(const uint4*)(sW + ((kt      ) << 9) + (lane << 3));
        f1.u = *(const uint4*)(sW + ((kt +  32) << 9) + (lane << 3));
        f2.u = *(const uint4*)(sW + ((kt +  64) << 9) + (lane << 3));
        acc[0] = __builtin_amdgcn_mfma_f32_16x16x32_bf16(ah[kt].b, f0.b, acc[0], 0, 0, 0);
        acc[0] = __builtin_amdgcn_mfma_f32_16x16x32_bf16(al[kt].b, f0.b, acc[0], 0, 0, 0);
        acc[1] = __builtin_amdgcn_mfma_f32_16x16x32_bf16(ah[kt].b, f1.b, acc[1], 0, 0, 0);
        acc[1] = __builtin_amdgcn_mfma_f32_16x16x32_bf16(al[kt].b, f1.b, acc[1], 0, 0, 0);
        acc[2] = __builtin_amdgcn_mfma_f32_16x16x32_bf16(ah[kt].b, f2.b, acc[2], 0, 0, 0);
        acc[2] = __builtin_amdgcn_mfma_f32_16x16x32_bf16(al[kt].b, f2.b, acc[2], 0, 0, 0);
      }

      if (LAYER == 1) {
#pragma unroll
        for (int r = 0; r < 4; ++r) {
          xr[r] = (float)xph[r * 3 + 0];
          xz[r] = (float)xph[r * 3 + 1];
          xn[r] = (float)xph[r * 3 + 2];
        }
      }

      // ---- gate math + sc1 h stores ----
      unsigned short* pHi = hhiS[po] + (size_t)bb * H_ + j;
      unsigned short* pLo = hloS[po] + (size_t)bb * H_ + j;
#pragma unroll
      for (int r = 0; r < 4; ++r) {
        const int b = bb + r;
        const float gr = acc[0][r] + bhr;
        const float gz = acc[1][r] + bhz;
        const float gn = acc[2][r] + bhn;
        const float rg = 1.f / (1.f + expf(-(xr[r] + gr)));
        const float zg = 1.f / (1.f + expf(-(xz[r] + gz)));
        const float ng = tanhf(xn[r] + rg * gn);
        const float hnew = (1.f - zg) * ng + zg * hprev[r];
        hprev[r] = hnew;

        const unsigned short hi = f2bf(hnew);
        const unsigned short lo = f2bf(hnew - bf2f(hi));
        STH(pHi + (size_t)r * H_, (uint32_t)hi);
        STH(pLo + (size_t)r * H_, (uint32_t)lo);

        const size_t yoff = ((size_t)b * T_ + t_eff) * 2048 + d * H_ + j;
        if (LAYER == 0) {
          ys0_hi[yoff] = hi;
          ys0_lo[yoff] = lo;
        } else {
          if (out_bf) out_b[yoff] = hi; else out_f[yoff] = hnew;
        }
        if (t == T_ - 1) {
          const size_t hh = HIDOFF + ((size_t)(LAYER * 2 + d) * B_ + b) * H_ + j;
          if (out_bf) out_b[hh] = hi; else out_f[hh] = hnew;
        }
      }

      if (t + 1 < T_) {
        // ---- prefetch x for t+1 BEFORE the barrier (latency under spin) ----
        const int te = d ? (T_ - 2 - t) : (t + 1);
        if (LAYER == 0) {
#pragma unroll
          for (int r = 0; r < 4; ++r) {
            const int tok = x[(bb + r) * T_ + te];
            xr[r] = sXr[tok] + bir; xz[r] = sXz[tok] + biz; xn[r] = sXn[tok] + bin_;
          }
        } else {
#pragma unroll
          for (int r = 0; r < 4; ++r) {
            const _Float16* xpb = xpd + ((size_t)(bb + r) * T_ + te) * G3_;
            xph[r * 3 + 0] = xpb[j]; xph[r * 3 + 1] = xpb[j + H_]; xph[r * 3 + 2] = xpb[j + 2 * H_];
          }
        }
        bar_fast(cnt, target);
      }
    }
  } else {
    // ==============  FENCED FALLBACK (fp32 inputs; correctness)  ===========
    for (int t = 0; t < T_; ++t) {
      const int t_eff = d ? (T_ - 1 - t) : t;
      const int pi = t & 1, po = pi ^ 1;

      float xr[4], xz[4], xn[4];
      if (LAYER == 0) {
#pragma unroll
        for (int r = 0; r < 4; ++r) {
          const int tok = x[(bb + r) * T_ + t_eff];
          xr[r] = sXr[tok] + bir; xz[r] = sXz[tok] + biz; xn[r] = sXn[tok] + bin_;
        }
      } else {
#pragma unroll
        for (int r = 0; r < 4; ++r) {
          const _Float16* xpb = xpd + ((size_t)(bb + r) * T_ + t_eff) * G3_;
          xr[r] = (float)xpb[j]; xz[r] = (float)xpb[j + H_]; xn[r] = (float)xpb[j + 2 * H_];
        }
      }

      const unsigned short* aph = aphS[pi];
      const unsigned short* apl = aplS[pi];
      f32x4 acc[3] = {};
#pragma unroll
      for (int kt = 0; kt < 32; ++kt) {
        FragU ah, al;
        ah.u = *(const uint4*)(aph + (kt << 5));
        al.u = *(const uint4*)(apl + (kt << 5));
#pragma unroll
        for (int g = 0; g < 3; ++g) {
          FragU fb, fl;
          fb.u = *(const uint4*)(sW + (((g << 5) + kt) << 9) + (lane << 3));
          fl.u = *(const uint4*)(bplG[g] + (kt << 5));
          acc[g] = __builtin_amdgcn_mfma_f32_16x16x32_bf16(ah.b, fb.b, acc[g], 0, 0, 0);
          acc[g] = __builtin_amdgcn_mfma_f32_16x16x32_bf16(al.b, fb.b, acc[g], 0, 0, 0);
          acc[g] = __builtin_amdgcn_mfma_f32_16x16x32_bf16(ah.b, fl.b, acc[g], 0, 0, 0);
        }
      }

#pragma unroll
      for (int r = 0; r < 4; ++r) {
        const int b = bb + r;
        const float gr = acc[0][r] + bhr;
        const float gz = acc[1][r] + bhz;
        const float gn = acc[2][r] + bhn;
        const float rg = 1.f / (1.f + expf(-(xr[r] + gr)));
        const float zg = 1.f / (1.f + expf(-(xz[r] + gz)));
        const float ng = tanhf(xn[r] + rg * gn);
        const float hnew = (1.f - zg) * ng + zg * hprev[r];
        hprev[r] = hnew;

        const size_t ho = (size_t)b * H_ + j;
        const unsigned short hi = f2bf(hnew);
        const unsigned short lo = f2bf(hnew - bf2f(hi));
        hhiS[po][ho] = hi;
        hloS[po][ho] = lo;

        const size_t yoff = ((size_t)b * T_ + t_eff) * 2048 + d * H_ + j;
        if (LAYER == 0) {
          ys0_hi[yoff] = hi;
          ys0_lo[yoff] = lo;
        } else {
          if (out_bf) out_b[yoff] = hi; else out_f[yoff] = hnew;
        }
        if (t == T_ - 1) {
          const size_t hh = HIDOFF + ((size_t)(LAYER * 2 + d) * B_ + b) * H_ + j;
          if (out_bf) out_b[hh] = hi; else out_f[hh] = hnew;
        }
      }

      if (t + 1 < T_) bar_fenced(cnt, target);
    }
  }
}

// ---------------------------------------------------------------------------
// xp1 = ys0cat @ Wih1[d]^T + bih1[d], fp16 out.  M=16384 N=3072 K=2048, x2 dirs.
// 128x128 tile, BK=32; A hi/lo always, B lo only when inputs were fp32.
// ---------------------------------------------------------------------------
__global__ __launch_bounds__(256) void xp1_gemm(
    const unsigned short* __restrict__ Ahi,    // (16384,2048) ys0 hi
    const unsigned short* __restrict__ Alo,    // ys0 lo
    const unsigned short* __restrict__ Bhi,    // (2,3072,2048) Wih1 hi
    const unsigned short* __restrict__ Blo,    // Wih1 lo
    const float*          __restrict__ biasf,  // (2,3072) fp32
    _Float16*             __restrict__ xp1,    // (2,16384,3072)
    const int*            __restrict__ flag)
{
  const int nt  = blockIdx.x;
  const int mt  = blockIdx.y;
  const int d   = blockIdx.z;
  const int tid = threadIdx.x;
  const int w = tid >> 6, lane = tid & 63;
  const int quad = lane >> 4, l15 = lane & 15;
  const int wm = w >> 1, wn = w & 1;
  const bool wlo = (*flag == 0);

  __shared__ unsigned short sAh[128][40];  // +8 pad: 80B row stride
  __shared__ unsigned short sAl[128][40];
  __shared__ unsigned short sBh[128][40];
  __shared__ unsigned short sBl[128][40];

  const int srow = tid >> 1;
  const int scol = (tid & 1) << 4;
  const unsigned short* gAh = Ahi + (size_t)(mt * 128 + srow) * 2048 + scol;
  const unsigned short* gAl = Alo + (size_t)(mt * 128 + srow) * 2048 + scol;
  const unsigned short* gBh = Bhi + (size_t)d * G3_ * 2048
                                  + (size_t)(nt * 128 + srow) * 2048 + scol;
  const unsigned short* gBl = Blo + (size_t)d * G3_ * 2048
                                  + (size_t)(nt * 128 + srow) * 2048 + scol;

  f32x4 acc[4][4] = {};

  for (int k0 = 0; k0 < 2048; k0 += 32) {
    const uint4 a0 = *(const uint4*)(gAh + k0);
    const uint4 a1 = *(const uint4*)(gAh + k0 + 8);
    const uint4 l0 = *(const uint4*)(gAl + k0);
    const uint4 l1 = *(const uint4*)(gAl + k0 + 8);
    const uint4 b0 = *(const uint4*)(gBh + k0);
    const uint4 b1 = *(const uint4*)(gBh + k0 + 8);
    uint4 c0, c1;
    if (wlo) { c0 = *(const uint4*)(gBl + k0); c1 = *(const uint4*)(gBl + k0 + 8); }
    __syncthreads();                       // previous iter's LDS reads done
    *(uint4*)&sAh[srow][scol]     = a0;
    *(uint4*)&sAh[srow][scol + 8] = a1;
    *(uint4*)&sAl[srow][scol]     = l0;
    *(uint4*)&sAl[srow][scol + 8] = l1;
    *(uint4*)&sBh[srow][scol]     = b0;
    *(uint4*)&sBh[srow][scol + 8] = b1;
    if (wlo) {
      *(uint4*)&sBl[srow][scol]     = c0;
      *(uint4*)&sBl[srow][scol + 8] = c1;
    }
    __syncthreads();

    bf16x8 fah[4], fal[4], fbh[4];
#pragma unroll
    for (int i = 0; i < 4; ++i) {
      FragU fa; fa.u = *(const uint4*)&sAh[(wm << 6) + (i << 4) + l15][quad << 3]; fah[i] = fa.b;
      FragU fl; fl.u = *(const uint4*)&sAl[(wm << 6) + (i << 4) + l15][quad << 3]; fal[i] = fl.b;
      FragU fb; fb.u = *(const uint4*)&sBh[(wn << 6) + (i << 4) + l15][quad << 3]; fbh[i] = fb.b;
    }
#pragma unroll
    for (int i = 0; i < 4; ++i)
#pragma unroll
      for (int jj = 0; jj < 4; ++jj) {
        acc[i][jj] = __builtin_amdgcn_mfma_f32_16x16x32_bf16(fah[i], fbh[jj], acc[i][jj], 0, 0, 0);
        acc[i][jj] = __builtin_amdgcn_mfma_f32_16x16x32_bf16(fal[i], fbh[jj], acc[i][jj], 0, 0, 0);
      }
    if (wlo) {
#pragma unroll
      for (int jj = 0; jj < 4; ++jj) {
        FragU fc; fc.u = *(const uint4*)&sBl[(wn << 6) + (jj << 4) + l15][quad << 3];
#pragma unroll
        for (int i = 0; i < 4; ++i)
          acc[i][jj] = __builtin_amdgcn_mfma_f32_16x16x32_bf16(fah[i], fc.b, acc[i][jj], 0, 0, 0);
      }
    }
  }

#pragma unroll
  for (int jj = 0; jj < 4; ++jj) {
    const int col = nt * 128 + (wn << 6) + (jj << 4) + l15;
    const float bias = biasf[(size_t)d * G3_ + col];
#pragma unroll
    for (int i = 0; i < 4; ++i) {
      const int m = mt * 128 + (wm << 6) + (i << 4) + (quad << 2);
      _Float16* op = xp1 + ((size_t)d * (B_ * T_) + m) * G3_ + col;
#pragma unroll
      for (int r = 0; r < 4; ++r) op[(size_t)r * G3_] = (_Float16)(acc[i][jj][r] + bias);
    }
  }
}

// ---------------------------------------------------------------------------
extern "C" void kernel_launch(void* const* d_in, const int* in_sizes, int n_in,
                              void* d_out, int out_size, void* d_ws, size_t ws_size,
                              hipStream_t stream)
{
  const int*  x    = (const int*)d_in[0];
  const void* Wih0 = d_in[1];   // (2,3072,128)
  const void* Whh0 = d_in[2];   // (2,3072,1024)
  const void* bih0 = d_in[3];   // (2,3072)
  const void* bhh0 = d_in[4];
  const void* Wih1 = d_in[5];   // (2,3072,2048)
  const void* Whh1 = d_in[6];   // (2,3072,1024)
  const void* bih1 = d_in[7];
  const void* bhh1 = d_in[8];

  // ---- workspace carve ----
  const size_t FLAG_B = 256;
  const size_t XP1_B  = (size_t)2 * B_ * T_ * G3_ * 2;    // fp16: 201,326,592
  const size_t YS_B   = (size_t)B_ * T_ * 2048 * 2;       // 67,108,864 (each)
  const size_t WHH_B  = (size_t)2 * G3_ * H_ * 2;         // 12,582,912 (each)
  const size_t WIH1_B = (size_t)2 * G3_ * 2048 * 2;       // 25,165,824 (each)
  const size_t WIH0_B = (size_t)2 * G3_ * 128 * 4;        // 3,145,728
  const size_t BIAS_B = (size_t)2 * G3_ * 4;              // 24,576 (each of 4)
  const size_t HB_B   = (size_t)2 * 2 * B_ * H_ * 2;      // 524,288 (each of hi/lo)
  const size_t BAR_B  = 4096;
  const size_t NEED = FLAG_B + XP1_B + 2 * YS_B + 4 * WHH_B + 2 * WIH1_B
                    + WIH0_B + 4 * BIAS_B + 2 * HB_B + BAR_B;
  if (ws_size < NEED) return;   // diagnostic: output stays zero

  char* p = (char*)d_ws;
  int*            flag    = (int*)p;            p += FLAG_B;
  _Float16*       xp1     = (_Float16*)p;       p += XP1_B;
  unsigned short* ys0_hi  = (unsigned short*)p; p += YS_B;
  unsigned short* ys0_lo  = (unsigned short*)p; p += YS_B;
  unsigned short* Whh0H   = (unsigned short*)p; p += WHH_B;
  unsigned short* Whh0L   = (unsigned short*)p; p += WHH_B;
  unsigned short* Whh1H   = (unsigned short*)p; p += WHH_B;
  unsigned short* Whh1L   = (unsigned short*)p; p += WHH_B;
  unsigned short* Wih1H   = (unsigned short*)p; p += WIH1_B;
  unsigned short* Wih1L   = (unsigned short*)p; p += WIH1_B;
  float*          Wih0f   = (float*)p;          p += WIH0_B;
  float*          bih0f   = (float*)p;          p += BIAS_B;
  float*          bhh0f   = (float*)p;          p += BIAS_B;
  float*          bih1f   = (float*)p;          p += BIAS_B;
  float*          bhh1f   = (float*)p;          p += BIAS_B;
  char*           hbase   = p;
  unsigned short* hhi     = (unsigned short*)hbase;
  unsigned short* hlo     = (unsigned short*)(hbase + HB_B);
  unsigned*       bar     = (unsigned*)(hbase + 2 * HB_B);

  // ---- allow 121KB dynamic LDS for the scan kernels (idempotent) ----
  hipFuncSetAttribute((const void*)&gru_scan<0>,
                      hipFuncAttributeMaxDynamicSharedMemorySize, SMEM_BYTES);
  hipFuncSetAttribute((const void*)&gru_scan<1>,
                      hipFuncAttributeMaxDynamicSharedMemorySize, SMEM_BYTES);

  // ---- dtype detect + canonicalize ----
  detect_dtype<<<1, 64, 0, stream>>>((const unsigned short*)bih0, flag);

  const int NWHH  = 2 * G3_ * H_;
  const int NWIH1 = 2 * G3_ * 2048;
  const int NWIH0 = 2 * G3_ * 128;
  const int NBIAS = 2 * G3_;
  prep_split<<<(NWHH  + 255) / 256, 256, 0, stream>>>(Whh0, NWHH,  Whh0H, Whh0L, flag);
  prep_split<<<(NWHH  + 255) / 256, 256, 0, stream>>>(Whh1, NWHH,  Whh1H, Whh1L, flag);
  prep_split<<<(NWIH1 + 255) / 256, 256, 0, stream>>>(Wih1, NWIH1, Wih1H, Wih1L, flag);
  prep_f32<<<(NWIH0 + 255) / 256, 256, 0, stream>>>(Wih0, NWIH0, Wih0f, flag);
  prep_f32<<<(NBIAS + 255) / 256, 256, 0, stream>>>(bih0, NBIAS, bih0f, flag);
  prep_f32<<<(NBIAS + 255) / 256, 256, 0, stream>>>(bhh0, NBIAS, bhh0f, flag);
  prep_f32<<<(NBIAS + 255) / 256, 256, 0, stream>>>(bih1, NBIAS, bih1f, flag);
  prep_f32<<<(NBIAS + 255) / 256, 256, 0, stream>>>(bhh1, NBIAS, bhh1f, flag);

  // ---- layer 0 scan (persistent, fence-free per-dir barrier) ----
  hipMemsetAsync(hbase, 0, 2 * HB_B + BAR_B, stream);
  gru_scan<0><<<dim3(64, 2), 256, SMEM_BYTES, stream>>>(
      x, Wih0f, bih0f, nullptr, Whh0H, Whh0L, bhh0f,
      hhi, hlo, ys0_hi, ys0_lo, d_out, flag, bar);

  // ---- layer-1 input projection ----
  xp1_gemm<<<dim3(24, 128, 2), 256, 0, stream>>>(ys0_hi, ys0_lo, Wih1H, Wih1L, bih1f, xp1, flag);

  // ---- layer 1 scan ----
  hipMemsetAsync(hbase, 0, 2 * HB_B + BAR_B, stream);
  gru_scan<1><<<dim3(64, 2), 256, SMEM_BYTES, stream>>>(
      x, nullptr, nullptr, xp1, Whh1H, Whh1L, bhh1f,
      hhi, hlo, nullptr, nullptr, d_out, flag, bar);
}